// Round 4
// baseline (420.476 us; speedup 1.0000x reference)
//
#include <hip/hip_runtime.h>

// Problem constants (B=32, C=3, H=480, W=640)
#define HW      307200     // H*W
#define HW4     76800      // HW/4 (float4 groups per plane)
#define CHW     921600     // 3*HW
#define FUSE_BPB 60        // one-pass: 60 blocks/batch * 256 thr * 5 iters * 4 == HW
#define RED_BPB 60         // fallback reduce blocks per batch
#define APP_BPB 300        // fallback apply blocks per batch
#define MAX_RESIDENT 2048  // 256 CU * 8 blocks/CU (VGPR<=64 via launch_bounds)

// native clang vector type — required by __builtin_nontemporal_store
typedef float vfloat4 __attribute__((ext_vector_type(4)));

struct RGB { float r, g, b; };

// ---------------------------------------------------------------------------
// Per-pixel pipeline: brightness -> contrast -> saturation -> hue
// ---------------------------------------------------------------------------
__device__ __forceinline__ RGB cr_process(
    float r, float g, float b,
    float bf, float cf, float sf, float hf, float cmean)
{
    // brightness
    r = fminf(fmaxf(r * bf, 0.0f), 1.0f);
    g = fminf(fmaxf(g * bf, 0.0f), 1.0f);
    b = fminf(fmaxf(b * bf, 0.0f), 1.0f);
    // contrast: cmean = (1-cf)*mean precomputed (uniform)
    r = fminf(fmaxf(cf * r + cmean, 0.0f), 1.0f);
    g = fminf(fmaxf(cf * g + cmean, 0.0f), 1.0f);
    b = fminf(fmaxf(cf * b + cmean, 0.0f), 1.0f);
    // saturation: blend with per-pixel gray
    float gray = 0.299f * r + 0.587f * g + 0.114f * b;
    float oms = (1.0f - sf) * gray;
    r = fminf(fmaxf(sf * r + oms, 0.0f), 1.0f);
    g = fminf(fmaxf(sf * g + oms, 0.0f), 1.0f);
    b = fminf(fmaxf(sf * b + oms, 0.0f), 1.0f);

    // hue adjust (RGB -> h,s,v -> shift h -> RGB)
    float maxc = fmaxf(r, fmaxf(g, b));
    float minc = fminf(r, fminf(g, b));
    float v  = maxc;
    float cr = maxc - minc;
    float crd = (cr == 0.0f) ? 1.0f : cr;
    float invcrd = 1.0f / crd;
    float md = (maxc == 0.0f) ? 1.0f : maxc;
    float s = cr / md;
    float rc = (maxc - r) * invcrd;
    float gc = (maxc - g) * invcrd;
    float bc = (maxc - b) * invcrd;

    float h = (maxc == r) ? (bc - gc)
            : ((maxc == g) ? (2.0f + rc - bc)
                           : (4.0f + gc - rc));
    h = h * (1.0f / 6.0f);
    h = h - floorf(h);      // python-style mod 1
    h = h + hf;
    h = h - floorf(h);

    float i6 = h * 6.0f;
    float fi = floorf(i6);
    float f  = i6 - fi;
    int i = ((int)fi) % 6;   // fi in [0,6]; 6 aliases to 0 with f==0 (continuous)

    float p = v * (1.0f - s);
    float q = v * (1.0f - f * s);
    float t = v * (1.0f - (1.0f - f) * s);

    RGB o;
    o.r = (i == 0 || i == 5) ? v : (i == 1 ? q : (i == 4 ? t : p));
    o.g = (i == 1 || i == 2) ? v : (i == 0 ? t : (i == 3 ? q : p));
    o.b = (i == 3 || i == 4) ? v : (i == 5 ? q : (i == 2 ? t : p));
    return o;
}

// ---------------------------------------------------------------------------
// Init: zero per-batch sum + arrival counters (workspace state is not trusted
// across harness poison fills). Device-scope stores so the main kernel's
// atomics observe them across XCDs.
// ---------------------------------------------------------------------------
__global__ void cr_init(float* bsum, unsigned* arrive, int nb)
{
    int i = threadIdx.x;
    if (i < nb) {
        __hip_atomic_store(&bsum[i], 0.0f, __ATOMIC_RELAXED, __HIP_MEMORY_SCOPE_AGENT);
        __hip_atomic_store(&arrive[i], 0u, __ATOMIC_RELAXED, __HIP_MEMORY_SCOPE_AGENT);
    }
}

// ---------------------------------------------------------------------------
// One-pass kernel with per-batch lock-free gate (regular launch, NOT coop).
// Block (b, blk):
//   phase 1: reduce its 1/60 slice -> atomicAdd(bsum[b]) -> fence ->
//            atomicAdd(arrive[b])
//   gate:    thread 0 spins (s_sleep) until arrive[b] == 60 (only its own
//            batch). Bounded spin as a safety valve.
//   phase 2: apply to the SAME slice (x re-read L2/L3-hot), NT stores.
// Co-residency: grid = B_out*60 <= 2048 at 8 blocks/CU (VGPR<=64 enforced);
// launcher falls back to the proven two-kernel path otherwise.
// ---------------------------------------------------------------------------
__global__ __launch_bounds__(256, 8) void cr_onepass(
    const float* __restrict__ x,
    const float* __restrict__ bright,
    const float* __restrict__ contrast,
    const float* __restrict__ sat,
    const float* __restrict__ hue,
    float* bsum,
    unsigned* arrive,
    float* __restrict__ out,
    int ns)
{
    int b   = blockIdx.x / FUSE_BPB;     // output-batch index (uniform per block)
    int blk = blockIdx.x % FUSE_BPB;
    int b_in = (ns == 1) ? b : (b / ns);

    const vfloat4* rp = (const vfloat4*)(x + (size_t)b_in * CHW);
    const vfloat4* gp = rp + HW4;
    const vfloat4* bp = gp + HW4;

    float bf = bright[b];

    // ---------------- phase 1: partial sum of gray(clip(x*bf)) -------------
    float acc = 0.0f;
    #pragma unroll
    for (int it = 0; it < 5; ++it) {
        int p = blk * 256 + (int)threadIdx.x + it * (FUSE_BPB * 256);
        vfloat4 r  = rp[p];
        vfloat4 g  = gp[p];
        vfloat4 bl = bp[p];
        #pragma unroll
        for (int k = 0; k < 4; ++k) {
            float rr = fminf(fmaxf(r[k]  * bf, 0.0f), 1.0f);
            float gg = fminf(fmaxf(g[k]  * bf, 0.0f), 1.0f);
            float bb = fminf(fmaxf(bl[k] * bf, 0.0f), 1.0f);
            acc += 0.299f * rr + 0.587f * gg + 0.114f * bb;
        }
    }

    // wave(64) shuffle reduce, then cross-wave via LDS
    #pragma unroll
    for (int off = 32; off > 0; off >>= 1)
        acc += __shfl_down(acc, off);

    __shared__ float wsum[4];
    __shared__ float smean_sh;
    int lane = threadIdx.x & 63;
    int wave = threadIdx.x >> 6;
    if (lane == 0) wsum[wave] = acc;
    __syncthreads();

    // ---------------- gate: publish partial, wait for batch peers ----------
    if (threadIdx.x == 0) {
        float part = wsum[0] + wsum[1] + wsum[2] + wsum[3];
        atomicAdd(&bsum[b], part);           // device-scope, cross-XCD coherent
        __threadfence();                     // sum visible before arrival
        atomicAdd(&arrive[b], 1u);

        int polls = 0;
        while (__hip_atomic_load(&arrive[b], __ATOMIC_ACQUIRE,
                                 __HIP_MEMORY_SCOPE_AGENT) < (unsigned)FUSE_BPB) {
            __builtin_amdgcn_s_sleep(2);
            if (++polls > (1 << 22)) break;  // safety valve: never hard-hang
        }
        smean_sh = __hip_atomic_load(&bsum[b], __ATOMIC_RELAXED,
                                     __HIP_MEMORY_SCOPE_AGENT) * (1.0f / (float)HW);
    }
    __syncthreads();
    float smean = smean_sh;

    // ---------------- phase 2: apply to the same slice ---------------------
    float cf = contrast[b];
    float sf = sat[b];
    float hf = hue[b];
    float cmean = (1.0f - cf) * smean;

    vfloat4* orp = (vfloat4*)(out + (size_t)b * CHW);
    vfloat4* ogp = orp + HW4;
    vfloat4* obp = ogp + HW4;

    #pragma unroll
    for (int it = 0; it < 5; ++it) {
        int p = blk * 256 + (int)threadIdx.x + it * (FUSE_BPB * 256);
        vfloat4 r  = rp[p];
        vfloat4 g  = gp[p];
        vfloat4 bl = bp[p];
        vfloat4 ro, go, bo;
        #pragma unroll
        for (int k = 0; k < 4; ++k) {
            RGB o = cr_process(r[k], g[k], bl[k], bf, cf, sf, hf, cmean);
            ro[k] = o.r;
            go[k] = o.g;
            bo[k] = o.b;
        }
        // non-temporal stores: out is never re-read; keep x resident in L2/L3
        __builtin_nontemporal_store(ro, &orp[p]);
        __builtin_nontemporal_store(go, &ogp[p]);
        __builtin_nontemporal_store(bo, &obp[p]);
    }
}

// ---------------------------------------------------------------------------
// Fallback: proven two-kernel path (226 µs baseline structure).
// ---------------------------------------------------------------------------
__global__ __launch_bounds__(256) void cr_reduce_gray(
    const float* __restrict__ x,
    const float* __restrict__ bright,
    float* __restrict__ part_ws,
    int ns)
{
    int b   = blockIdx.x / RED_BPB;
    int blk = blockIdx.x % RED_BPB;
    int b_in = (ns == 1) ? b : (b / ns);

    const vfloat4* rp = (const vfloat4*)(x + (size_t)b_in * CHW);
    const vfloat4* gp = rp + HW4;
    const vfloat4* bp = gp + HW4;
    float bf = bright[b];

    float acc = 0.0f;
    #pragma unroll
    for (int it = 0; it < 5; ++it) {
        int p = blk * 256 + threadIdx.x + it * (RED_BPB * 256);
        vfloat4 r  = rp[p];
        vfloat4 g  = gp[p];
        vfloat4 bl = bp[p];
        #pragma unroll
        for (int k = 0; k < 4; ++k) {
            float rr = fminf(fmaxf(r[k]  * bf, 0.0f), 1.0f);
            float gg = fminf(fmaxf(g[k]  * bf, 0.0f), 1.0f);
            float bb = fminf(fmaxf(bl[k] * bf, 0.0f), 1.0f);
            acc += 0.299f * rr + 0.587f * gg + 0.114f * bb;
        }
    }

    #pragma unroll
    for (int off = 32; off > 0; off >>= 1)
        acc += __shfl_down(acc, off);

    __shared__ float wsum[4];
    int lane = threadIdx.x & 63;
    int wave = threadIdx.x >> 6;
    if (lane == 0) wsum[wave] = acc;
    __syncthreads();
    if (threadIdx.x == 0)
        part_ws[b * RED_BPB + blk] = wsum[0] + wsum[1] + wsum[2] + wsum[3];
}

__global__ __launch_bounds__(256) void cr_apply(
    const float* __restrict__ x,
    const float* __restrict__ bright,
    const float* __restrict__ contrast,
    const float* __restrict__ sat,
    const float* __restrict__ hue,
    const float* __restrict__ part_ws,
    float* __restrict__ out,
    int ns)
{
    int b    = blockIdx.x / APP_BPB;
    int pblk = blockIdx.x % APP_BPB;
    int p4   = pblk * 256 + threadIdx.x;
    int b_in = (ns == 1) ? b : (b / ns);

    __shared__ float smean;
    if (threadIdx.x < 64) {
        float v = (threadIdx.x < RED_BPB) ? part_ws[b * RED_BPB + threadIdx.x] : 0.0f;
        #pragma unroll
        for (int off = 32; off > 0; off >>= 1)
            v += __shfl_down(v, off);
        if (threadIdx.x == 0) smean = v * (1.0f / (float)HW);
    }
    __syncthreads();

    const vfloat4* rp = (const vfloat4*)(x + (size_t)b_in * CHW);
    const vfloat4* gp = rp + HW4;
    const vfloat4* bp = gp + HW4;
    vfloat4* orp = (vfloat4*)(out + (size_t)b * CHW);
    vfloat4* ogp = orp + HW4;
    vfloat4* obp = ogp + HW4;

    float bf = bright[b];
    float cf = contrast[b];
    float sf = sat[b];
    float hf = hue[b];
    float cmean = (1.0f - cf) * smean;

    vfloat4 r  = rp[p4];
    vfloat4 g  = gp[p4];
    vfloat4 bl = bp[p4];
    vfloat4 ro, go, bo;

    #pragma unroll
    for (int k = 0; k < 4; ++k) {
        RGB o = cr_process(r[k], g[k], bl[k], bf, cf, sf, hf, cmean);
        ro[k] = o.r;
        go[k] = o.g;
        bo[k] = o.b;
    }

    __builtin_nontemporal_store(ro, &orp[p4]);
    __builtin_nontemporal_store(go, &ogp[p4]);
    __builtin_nontemporal_store(bo, &obp[p4]);
}

extern "C" void kernel_launch(void* const* d_in, const int* in_sizes, int n_in,
                              void* d_out, int out_size, void* d_ws, size_t ws_size,
                              hipStream_t stream) {
    const float* x  = (const float*)d_in[0];
    const float* bf = (const float*)d_in[1];
    const float* cf = (const float*)d_in[2];
    const float* sf = (const float*)d_in[3];
    const float* hf = (const float*)d_in[4];
    float* out = (float*)d_out;

    int ns = out_size / in_sizes[0];
    if (ns < 1) ns = 1;
    int B_out = out_size / CHW;

    // workspace layout: bsum = first 64 floats, arrive = next 64 unsigned
    float*    bsum   = (float*)d_ws;
    unsigned* arrive = (unsigned*)((char*)d_ws + 64 * sizeof(float));

    // One-pass gated path requires full co-residency: grid <= 2048 blocks at
    // 8 blocks/CU (VGPR<=64 via __launch_bounds__(256,8)). 32*60=1920 fits.
    if (B_out * FUSE_BPB <= MAX_RESIDENT && B_out <= 64 &&
        ws_size >= 64 * (sizeof(float) + sizeof(unsigned))) {
        cr_init<<<dim3(1), dim3(64), 0, stream>>>(bsum, arrive, B_out);
        cr_onepass<<<dim3(B_out * FUSE_BPB), dim3(256), 0, stream>>>(
            x, bf, cf, sf, hf, bsum, arrive, out, ns);
    } else {
        float* part_ws = (float*)d_ws;   // B_out * RED_BPB floats
        cr_reduce_gray<<<dim3(B_out * RED_BPB), dim3(256), 0, stream>>>(
            x, bf, part_ws, ns);
        cr_apply<<<dim3(B_out * APP_BPB), dim3(256), 0, stream>>>(
            x, bf, cf, sf, hf, part_ws, out, ns);
    }
}

// Round 5
// 228.484 us; speedup vs baseline: 1.8403x; 1.8403x over previous
//
#include <hip/hip_runtime.h>

// Problem constants (B=32, C=3, H=480, W=640)
#define HW      307200     // H*W
#define HW4     76800      // HW/4 (float4 groups per plane)
#define CHW     921600     // 3*HW
#define RED_BPB 60         // reduce blocks per batch: 60*256*5*4 == HW exactly
#define APP_BPB 300        // apply blocks per batch: 300*256   == HW4 exactly

typedef float vfloat4 __attribute__((ext_vector_type(4)));

struct RGB { float r, g, b; };

// ---------------------------------------------------------------------------
// Pass 1 (PROVEN, unchanged): per-batch partial sums of gray(clip(x*bf,0,1)).
// Block (b, blk) writes its partial to ws[b*RED_BPB + blk]. No atomics,
// no memset needed (every slot is written every call).
// ---------------------------------------------------------------------------
__global__ __launch_bounds__(256) void cr_reduce_gray(
    const float* __restrict__ x,
    const float* __restrict__ bright,
    float* __restrict__ part_ws,
    int ns)
{
    int b   = blockIdx.x / RED_BPB;     // output-batch index (uniform)
    int blk = blockIdx.x % RED_BPB;
    int b_in = (ns == 1) ? b : (b / ns);

    const vfloat4* rp = (const vfloat4*)(x + (size_t)b_in * CHW);
    const vfloat4* gp = rp + HW4;
    const vfloat4* bp = gp + HW4;
    float bf = bright[b];

    float acc = 0.0f;
    #pragma unroll
    for (int it = 0; it < 5; ++it) {
        int p = blk * 256 + threadIdx.x + it * (RED_BPB * 256);
        vfloat4 r  = rp[p];
        vfloat4 g  = gp[p];
        vfloat4 bl = bp[p];
        #pragma unroll
        for (int k = 0; k < 4; ++k) {
            float rr = fminf(fmaxf(r[k]  * bf, 0.0f), 1.0f);
            float gg = fminf(fmaxf(g[k]  * bf, 0.0f), 1.0f);
            float bb = fminf(fmaxf(bl[k] * bf, 0.0f), 1.0f);
            acc += 0.299f * rr + 0.587f * gg + 0.114f * bb;
        }
    }

    // wave(64) shuffle reduce
    #pragma unroll
    for (int off = 32; off > 0; off >>= 1)
        acc += __shfl_down(acc, off);

    __shared__ float wsum[4];
    int lane = threadIdx.x & 63;
    int wave = threadIdx.x >> 6;
    if (lane == 0) wsum[wave] = acc;
    __syncthreads();
    if (threadIdx.x == 0)
        part_ws[b * RED_BPB + blk] = wsum[0] + wsum[1] + wsum[2] + wsum[3];
}

// ---------------------------------------------------------------------------
// Per-pixel pipeline: brightness -> contrast -> saturation -> hue
// ---------------------------------------------------------------------------
__device__ __forceinline__ RGB cr_process(
    float r, float g, float b,
    float bf, float cf, float sf, float hf, float cmean)
{
    // brightness
    r = fminf(fmaxf(r * bf, 0.0f), 1.0f);
    g = fminf(fmaxf(g * bf, 0.0f), 1.0f);
    b = fminf(fmaxf(b * bf, 0.0f), 1.0f);
    // contrast: cmean = (1-cf)*mean precomputed (uniform)
    r = fminf(fmaxf(cf * r + cmean, 0.0f), 1.0f);
    g = fminf(fmaxf(cf * g + cmean, 0.0f), 1.0f);
    b = fminf(fmaxf(cf * b + cmean, 0.0f), 1.0f);
    // saturation: blend with per-pixel gray
    float gray = 0.299f * r + 0.587f * g + 0.114f * b;
    float oms = (1.0f - sf) * gray;
    r = fminf(fmaxf(sf * r + oms, 0.0f), 1.0f);
    g = fminf(fmaxf(sf * g + oms, 0.0f), 1.0f);
    b = fminf(fmaxf(sf * b + oms, 0.0f), 1.0f);

    // hue adjust (RGB -> h,s,v -> shift h -> RGB)
    float maxc = fmaxf(r, fmaxf(g, b));
    float minc = fminf(r, fminf(g, b));
    float v  = maxc;
    float cr = maxc - minc;
    float crd = (cr == 0.0f) ? 1.0f : cr;
    float invcrd = 1.0f / crd;
    float md = (maxc == 0.0f) ? 1.0f : maxc;
    float s = cr / md;
    float rc = (maxc - r) * invcrd;
    float gc = (maxc - g) * invcrd;
    float bc = (maxc - b) * invcrd;

    float h = (maxc == r) ? (bc - gc)
            : ((maxc == g) ? (2.0f + rc - bc)
                           : (4.0f + gc - rc));
    h = h * (1.0f / 6.0f);
    h = h - floorf(h);      // python-style mod 1
    h = h + hf;
    h = h - floorf(h);

    float i6 = h * 6.0f;
    float fi = floorf(i6);
    float f  = i6 - fi;
    int i = ((int)fi) % 6;   // fi in [0,6]; 6 aliases to 0 with f==0 (continuous)

    float p = v * (1.0f - s);
    float q = v * (1.0f - f * s);
    float t = v * (1.0f - (1.0f - f) * s);

    RGB o;
    o.r = (i == 0 || i == 5) ? v : (i == 1 ? q : (i == 4 ? t : p));
    o.g = (i == 1 || i == 2) ? v : (i == 0 ? t : (i == 3 ? q : p));
    o.b = (i == 3 || i == 4) ? v : (i == 5 ? q : (i == 2 ? t : p));
    return o;
}

// ---------------------------------------------------------------------------
// Pass 2: EXACT R0 proven apply, single variable changed:
// plain stores instead of __builtin_nontemporal_store.
// Rationale: harness fills prove plain stores hit 6.8 TB/s; apply's effective
// write rate with NT was ~1.7-2 TB/s. NT bypasses the L2 write-back path.
// out is never re-read, but L2 allocation of out is harmless (write-back at
// full rate; x stream is not reused within the kernel).
// ---------------------------------------------------------------------------
__global__ __launch_bounds__(256) void cr_apply(
    const float* __restrict__ x,
    const float* __restrict__ bright,
    const float* __restrict__ contrast,
    const float* __restrict__ sat,
    const float* __restrict__ hue,
    const float* __restrict__ part_ws,
    float* __restrict__ out,
    int ns)
{
    int b    = blockIdx.x / APP_BPB;          // uniform per block
    int pblk = blockIdx.x % APP_BPB;
    int p4   = pblk * 256 + threadIdx.x;
    int b_in = (ns == 1) ? b : (b / ns);

    // broadcast mean: one wave sums the 60 partials
    __shared__ float smean;
    if (threadIdx.x < 64) {
        float v = (threadIdx.x < RED_BPB) ? part_ws[b * RED_BPB + threadIdx.x] : 0.0f;
        #pragma unroll
        for (int off = 32; off > 0; off >>= 1)
            v += __shfl_down(v, off);
        if (threadIdx.x == 0) smean = v * (1.0f / (float)HW);
    }
    __syncthreads();

    const vfloat4* rp = (const vfloat4*)(x + (size_t)b_in * CHW);
    const vfloat4* gp = rp + HW4;
    const vfloat4* bp = gp + HW4;
    vfloat4* orp = (vfloat4*)(out + (size_t)b * CHW);
    vfloat4* ogp = orp + HW4;
    vfloat4* obp = ogp + HW4;

    float bf = bright[b];
    float cf = contrast[b];
    float sf = sat[b];
    float hf = hue[b];
    float cmean = (1.0f - cf) * smean;

    vfloat4 r  = rp[p4];
    vfloat4 g  = gp[p4];
    vfloat4 bl = bp[p4];
    vfloat4 ro, go, bo;

    #pragma unroll
    for (int k = 0; k < 4; ++k) {
        RGB o = cr_process(r[k], g[k], bl[k], bf, cf, sf, hf, cmean);
        ro[k] = o.r;
        go[k] = o.g;
        bo[k] = o.b;
    }

    // plain stores (the single change vs the 226 µs baseline)
    orp[p4] = ro;
    ogp[p4] = go;
    obp[p4] = bo;
}

extern "C" void kernel_launch(void* const* d_in, const int* in_sizes, int n_in,
                              void* d_out, int out_size, void* d_ws, size_t ws_size,
                              hipStream_t stream) {
    const float* x  = (const float*)d_in[0];
    const float* bf = (const float*)d_in[1];
    const float* cf = (const float*)d_in[2];
    const float* sf = (const float*)d_in[3];
    const float* hf = (const float*)d_in[4];
    float* out = (float*)d_out;

    int ns = out_size / in_sizes[0];
    if (ns < 1) ns = 1;
    int B_out = out_size / CHW;

    float* part_ws = (float*)d_ws;   // B_out * RED_BPB floats, fully rewritten each call

    cr_reduce_gray<<<dim3(B_out * RED_BPB), dim3(256), 0, stream>>>(
        x, bf, part_ws, ns);

    cr_apply<<<dim3(B_out * APP_BPB), dim3(256), 0, stream>>>(
        x, bf, cf, sf, hf, part_ws, out, ns);
}